// Round 1
// baseline (384.619 us; speedup 1.0000x reference)
//
#include <hip/hip_runtime.h>

typedef unsigned int uint;
typedef unsigned short ushort;

#define DEV static __device__ __forceinline__

DEV float bf_lo(uint v) { return __uint_as_float(v << 16); }
DEV float bf_hi(uint v) { return __uint_as_float(v & 0xffff0000u); }
DEV ushort f2bf(float f) {
    uint u = __float_as_uint(f);
    u += 0x7fffu + ((u >> 16) & 1u);   // round-to-nearest-even
    return (ushort)(u >> 16);
}

DEV float ldA(const float* p, size_t i) { return p[i]; }
DEV float ldA(const ushort* p, size_t i) { return __uint_as_float(((uint)p[i]) << 16); }
DEV void stC(float* p, float v) { *p = v; }
DEV void stC(ushort* p, float v) { *p = f2bf(v); }

// ---------------------------------------------------------------------------
// MP[i, c]:  c <  1024 -> M_h[i,j] = (1/sqrt(128)) * sum_a Wq[i,h*128+a]*Wk[j,h*128+a]
//            c >= 1024 -> P_h[i,j] =                 sum_a Wv[i,h*128+a]*Wo[h*128+a, j]
// with h = (c>>7)&7, j = c&127
// ---------------------------------------------------------------------------
__global__ void build_mp_kernel(const float* __restrict__ Wq, const float* __restrict__ Wk,
                                const float* __restrict__ Wv, const float* __restrict__ Wo,
                                float* __restrict__ MP)
{
    int idx = blockIdx.x * 256 + threadIdx.x;
    if (idx >= 128 * 2048) return;
    int i = idx >> 11;
    int c = idx & 2047;
    int h = (c >> 7) & 7;
    int j = c & 127;
    float s = 0.f;
    if (c < 1024) {
        const float* a = Wq + i * 1024 + h * 128;
        const float* b = Wk + j * 1024 + h * 128;
#pragma unroll 8
        for (int t = 0; t < 128; ++t) s += a[t] * b[t];
        s *= 0.08838834764831845f;  // 1/sqrt(128)
    } else {
        const float* a = Wv + i * 1024 + h * 128;
        const float* b = Wo + (h * 128) * 128 + j;
#pragma unroll 8
        for (int t = 0; t < 128; ++t) s += a[t] * b[(size_t)t * 128];
    }
    MP[idx] = s;
}

// ---------------------------------------------------------------------------
// Generic tiled GEMM: C(M,NC) = A(M,K) @ B(K,NC)  [+ bias] [relu] [+ res]
// 64x64 tile, 256 threads, 4x4 per thread, K-chunks of 64.
// As stored transposed (As[k][row]) so inner loop is 2x ds_read_b128.
// ---------------------------------------------------------------------------
template <typename AT, typename OT, bool BIAS, bool RELU, bool RES>
__global__ __launch_bounds__(256) void gemm_tile(
    const AT* __restrict__ A, const float* __restrict__ B,
    const float* __restrict__ bias, const float* __restrict__ res,
    OT* __restrict__ C, int M, int K, int NC)
{
    __shared__ float As[64][68];  // [k][row]
    __shared__ float Bs[64][68];  // [k][col]
    const int m0 = blockIdx.x * 64;
    const int n0 = blockIdx.y * 64;
    const int t = threadIdx.x;
    const int ty = t >> 4, tx = t & 15;

    float acc[4][4] = {};

    for (int kk = 0; kk < K; kk += 64) {
#pragma unroll
        for (int i = 0; i < 16; ++i) {
            int idx = i * 256 + t;
            int r = idx >> 6, c = idx & 63;
            int gm = m0 + r;
            As[c][r] = (gm < M) ? ldA(A, (size_t)gm * K + kk + c) : 0.f;
            Bs[r][c] = B[(size_t)(kk + r) * NC + n0 + c];
        }
        __syncthreads();
#pragma unroll
        for (int k = 0; k < 64; ++k) {
            float4 av = *reinterpret_cast<const float4*>(&As[k][ty * 4]);
            float4 bv = *reinterpret_cast<const float4*>(&Bs[k][tx * 4]);
            acc[0][0] += av.x * bv.x; acc[0][1] += av.x * bv.y; acc[0][2] += av.x * bv.z; acc[0][3] += av.x * bv.w;
            acc[1][0] += av.y * bv.x; acc[1][1] += av.y * bv.y; acc[1][2] += av.y * bv.z; acc[1][3] += av.y * bv.w;
            acc[2][0] += av.z * bv.x; acc[2][1] += av.z * bv.y; acc[2][2] += av.z * bv.z; acc[2][3] += av.z * bv.w;
            acc[3][0] += av.w * bv.x; acc[3][1] += av.w * bv.y; acc[3][2] += av.w * bv.z; acc[3][3] += av.w * bv.w;
        }
        __syncthreads();
    }

#pragma unroll
    for (int i = 0; i < 4; ++i) {
        int gm = m0 + ty * 4 + i;
        if (gm >= M) continue;
#pragma unroll
        for (int j = 0; j < 4; ++j) {
            int gn = n0 + tx * 4 + j;
            float v = acc[i][j];
            if (BIAS) v += bias[gn];
            if (RELU) v = fmaxf(v, 0.f);
            if (RES) v += res[(size_t)gm * NC + gn];
            stC(&C[(size_t)gm * NC + gn], v);
        }
    }
}

// ---------------------------------------------------------------------------
// Edge pass 1: one wave per edge. u[e,h] = dot(G[dst,h,:], feat[src,:]),
// clamp +-5 (scale already folded into M), ex = exp(u); store ex, atomicAdd den.
// ---------------------------------------------------------------------------
__global__ __launch_bounds__(256) void edge_logits_kernel(
    const float* __restrict__ feat, const ushort* __restrict__ GVO,
    const int* __restrict__ src, const int* __restrict__ dst,
    float* __restrict__ exb, float* __restrict__ den, int E)
{
    int wid = (int)((blockIdx.x * 256 + threadIdx.x) >> 6);
    int lane = threadIdx.x & 63;
    if (wid >= E) return;
    int s = src[wid], d = dst[wid];
    float2 f = reinterpret_cast<const float2*>(feat)[(size_t)s * 64 + lane];
    float myex = 0.f;
#pragma unroll
    for (int h = 0; h < 8; ++h) {
        uint gv = *reinterpret_cast<const uint*>(&GVO[(size_t)d * 2048 + h * 128 + 2 * lane]);
        float p = bf_lo(gv) * f.x + bf_hi(gv) * f.y;
#pragma unroll
        for (int off = 32; off; off >>= 1) p += __shfl_xor(p, off);
        float u = fminf(fmaxf(p, -5.f), 5.f);
        float ex = __expf(u);
        if (lane == h) myex = ex;
    }
    if (lane < 8) {
        exb[(size_t)wid * 8 + lane] = myex;
        atomicAdd(&den[(size_t)d * 8 + lane], myex);
    }
}

// ---------------------------------------------------------------------------
// Edge pass 2: one wave per edge. attn[dst,:] += sum_h a_eh * VO[src,h,:]
// ---------------------------------------------------------------------------
__global__ __launch_bounds__(256) void edge_agg_kernel(
    const ushort* __restrict__ GVO, const int* __restrict__ src,
    const int* __restrict__ dst, const float* __restrict__ exb,
    const float* __restrict__ den, float* __restrict__ attn, int E)
{
    int wid = (int)((blockIdx.x * 256 + threadIdx.x) >> 6);
    int lane = threadIdx.x & 63;
    if (wid >= E) return;
    int s = src[wid], d = dst[wid];
    float aval = 0.f;
    if (lane < 8) aval = exb[(size_t)wid * 8 + lane] / den[(size_t)d * 8 + lane];
    float acc0 = 0.f, acc1 = 0.f;
#pragma unroll
    for (int h = 0; h < 8; ++h) {
        float a = __shfl(aval, h);
        uint gv = *reinterpret_cast<const uint*>(&GVO[(size_t)s * 2048 + 1024 + h * 128 + 2 * lane]);
        acc0 += a * bf_lo(gv);
        acc1 += a * bf_hi(gv);
    }
    atomicAdd(&attn[(size_t)d * 128 + 2 * lane], acc0);
    atomicAdd(&attn[(size_t)d * 128 + 2 * lane + 1], acc1);
}

// ---------------------------------------------------------------------------
// LayerNorm over rows of 128. One wave per row. Optional second addend.
// ---------------------------------------------------------------------------
template <bool TWO>
__global__ __launch_bounds__(256) void ln_kernel(
    const float* __restrict__ x, const float* __restrict__ y,
    const float* __restrict__ g, const float* __restrict__ b,
    float* __restrict__ out, int M)
{
    int row = (int)((blockIdx.x * 256 + threadIdx.x) >> 6);
    int lane = threadIdx.x & 63;
    if (row >= M) return;
    float2 v = reinterpret_cast<const float2*>(x)[(size_t)row * 64 + lane];
    if (TWO) {
        float2 w = reinterpret_cast<const float2*>(y)[(size_t)row * 64 + lane];
        v.x += w.x; v.y += w.y;
    }
    float sum = v.x + v.y;
#pragma unroll
    for (int off = 32; off; off >>= 1) sum += __shfl_xor(sum, off);
    float mean = sum * (1.f / 128.f);
    float cx = v.x - mean, cy = v.y - mean;
    float vs = cx * cx + cy * cy;
#pragma unroll
    for (int off = 32; off; off >>= 1) vs += __shfl_xor(vs, off);
    float r = rsqrtf(vs * (1.f / 128.f) + 1e-5f);
    float2 gg = reinterpret_cast<const float2*>(g)[lane];
    float2 bb = reinterpret_cast<const float2*>(b)[lane];
    float2 o;
    o.x = cx * r * gg.x + bb.x;
    o.y = cy * r * gg.y + bb.y;
    reinterpret_cast<float2*>(out)[(size_t)row * 64 + lane] = o;
}

// ---------------------------------------------------------------------------
extern "C" void kernel_launch(void* const* d_in, const int* in_sizes, int n_in,
                              void* d_out, int out_size, void* d_ws, size_t ws_size,
                              hipStream_t stream)
{
    const float* feat = (const float*)d_in[0];
    const int*   src  = (const int*)d_in[1];
    const int*   dst  = (const int*)d_in[2];
    const float* Wq   = (const float*)d_in[3];
    const float* Wk   = (const float*)d_in[4];
    const float* Wv   = (const float*)d_in[5];
    const float* Wo   = (const float*)d_in[6];
    const float* g1   = (const float*)d_in[7];
    const float* b1   = (const float*)d_in[8];
    const float* W1   = (const float*)d_in[9];
    const float* bf1  = (const float*)d_in[10];
    const float* W2   = (const float*)d_in[11];
    const float* bf2  = (const float*)d_in[12];
    const float* g2   = (const float*)d_in[13];
    const float* b2   = (const float*)d_in[14];
    const int N = in_sizes[0] / 128;
    const int E = in_sizes[1];
    float* out = (float*)d_out;

    char* w = (char*)d_ws;
    auto alloc = [&](size_t bytes) {
        char* p = w;
        w += (bytes + 255) & ~(size_t)255;
        return p;
    };
    float*  MP   = (float*)alloc((size_t)128 * 2048 * 4);
    ushort* GVO  = (ushort*)alloc((size_t)N * 2048 * 2);
    float*  exb  = (float*)alloc((size_t)E * 8 * 4);
    float*  den  = (float*)alloc((size_t)N * 8 * 4);
    float*  attn = (float*)alloc((size_t)N * 128 * 4);
    float*  uh   = (float*)alloc((size_t)N * 128 * 4);
    ushort* f1   = (ushort*)alloc((size_t)N * 512 * 2);
    float*  pre2 = (float*)alloc((size_t)N * 128 * 4);

    hipMemsetAsync(den, 0, (size_t)N * 8 * 4, stream);
    hipMemsetAsync(attn, 0, (size_t)N * 128 * 4, stream);

    build_mp_kernel<<<(128 * 2048 + 255) / 256, 256, 0, stream>>>(Wq, Wk, Wv, Wo, MP);

    dim3 gv_grid((N + 63) / 64, 2048 / 64);
    gemm_tile<float, ushort, false, false, false><<<gv_grid, 256, 0, stream>>>(
        feat, MP, nullptr, nullptr, GVO, N, 128, 2048);

    int eblocks = (E + 3) / 4;
    edge_logits_kernel<<<eblocks, 256, 0, stream>>>(feat, GVO, src, dst, exb, den, E);
    edge_agg_kernel<<<eblocks, 256, 0, stream>>>(GVO, src, dst, exb, den, attn, E);

    int lblocks = (N + 3) / 4;
    ln_kernel<true><<<lblocks, 256, 0, stream>>>(feat, attn, g1, b1, uh, N);

    dim3 f1_grid((N + 63) / 64, 512 / 64);
    gemm_tile<float, ushort, true, true, false><<<f1_grid, 256, 0, stream>>>(
        uh, W1, bf1, nullptr, f1, N, 128, 512);

    dim3 f2_grid((N + 63) / 64, 128 / 64);
    gemm_tile<ushort, float, true, false, true><<<f2_grid, 256, 0, stream>>>(
        f1, W2, bf2, uh, pre2, N, 512, 128);

    ln_kernel<false><<<lblocks, 256, 0, stream>>>(pre2, nullptr, g2, b2, out, N);
}

// Round 2
// 215.223 us; speedup vs baseline: 1.7871x; 1.7871x over previous
//
#include <hip/hip_runtime.h>

typedef unsigned int uint;
typedef unsigned short ushort;
typedef __attribute__((ext_vector_type(8))) short short8;
typedef __attribute__((ext_vector_type(4))) float f32x4;

#define DEV static __device__ __forceinline__

DEV float bf_lo(uint v) { return __uint_as_float(v << 16); }
DEV float bf_hi(uint v) { return __uint_as_float(v & 0xffff0000u); }
DEV ushort f2bf(float f) {
    uint u = __float_as_uint(f);
    u += 0x7fffu + ((u >> 16) & 1u);   // round-to-nearest-even
    return (ushort)(u >> 16);
}
DEV void stC(float* p, float v) { *p = v; }
DEV void stC(ushort* p, float v) { *p = f2bf(v); }

// ---------------------------------------------------------------------------
// fp32 -> bf16 bulk convert (4 elems/thread)
// ---------------------------------------------------------------------------
__global__ void f2bf_kernel(const float* __restrict__ in, ushort* __restrict__ out, int n4)
{
    int i = blockIdx.x * 256 + threadIdx.x;
    if (i >= n4) return;
    float4 v = reinterpret_cast<const float4*>(in)[i];
    ushort4 o;
    o.x = f2bf(v.x); o.y = f2bf(v.y); o.z = f2bf(v.z); o.w = f2bf(v.w);
    reinterpret_cast<ushort4*>(out)[i] = o;
}

// ---------------------------------------------------------------------------
// transpose + convert: outT[n*K + k] = bf16(in[k*NC + n])
// ---------------------------------------------------------------------------
__global__ void transp_bf_kernel(const float* __restrict__ in, ushort* __restrict__ outT,
                                 int K, int NC)
{
    int tid = blockIdx.x * 256 + threadIdx.x;
    if (tid >= K * NC) return;
    int n = tid % NC, k = tid / NC;
    outT[(size_t)n * K + k] = f2bf(in[tid]);
}

// ---------------------------------------------------------------------------
// MPT[c, i] (bf16, [2048][128] = B^T for the GVO gemm):
//  c <  1024 -> M_h[i,j] = (1/sqrt(128)) * sum_a Wq[i,h*128+a]*Wk[j,h*128+a]
//  c >= 1024 -> P_h[i,j] =                 sum_a Wv[i,h*128+a]*Wo[h*128+a, j]
//  h = (c>>7)&7, j = c&127
// ---------------------------------------------------------------------------
__global__ void build_mpt_kernel(const float* __restrict__ Wq, const float* __restrict__ Wk,
                                 const float* __restrict__ Wv, const float* __restrict__ Wo,
                                 ushort* __restrict__ MPT)
{
    int idx = blockIdx.x * 256 + threadIdx.x;
    if (idx >= 128 * 2048) return;
    int i = idx >> 11;
    int c = idx & 2047;
    int h = (c >> 7) & 7;
    int j = c & 127;
    float s = 0.f;
    if (c < 1024) {
        const float* a = Wq + i * 1024 + h * 128;
        const float* b = Wk + j * 1024 + h * 128;
#pragma unroll 8
        for (int t = 0; t < 128; ++t) s += a[t] * b[t];
        s *= 0.08838834764831845f;  // 1/sqrt(128)
    } else {
        const float* a = Wv + i * 1024 + h * 128;
        const float* b = Wo + (h * 128) * 128 + j;
#pragma unroll 8
        for (int t = 0; t < 128; ++t) s += a[t] * b[(size_t)t * 128];
    }
    MPT[(size_t)c * 128 + i] = f2bf(s);
}

// ---------------------------------------------------------------------------
// bf16 MFMA GEMM: C(M,NC) = A(M,K) @ BT(NC,K)^T  [+bias][relu][+res]
// 128x64 tile, 256 threads (4 waves, 2x2), BK=64, XOR-swizzled LDS.
// ---------------------------------------------------------------------------
template <typename OT, bool BIAS, bool RELU, bool RES>
__global__ __launch_bounds__(256) void gemm_mfma(
    const ushort* __restrict__ A, const ushort* __restrict__ BT,
    const float* __restrict__ bias, const float* __restrict__ res,
    OT* __restrict__ C, int M, int K, int NC)
{
    __shared__ char lds[24576];
    char* AsB = lds;            // 128 rows x 128B (64 bf16/row), XOR swizzled
    char* BsB = lds + 16384;    // 64 rows x 128B

    const int m0 = blockIdx.y * 128;
    const int n0 = blockIdx.x * 64;
    const int t = threadIdx.x;
    const int lane = t & 63, wid = t >> 6;
    const int wm = wid >> 1, wn = wid & 1;
    const int frow = lane & 15, kgrp = lane >> 4;

    f32x4 acc[4][2] = {};

    for (int kk = 0; kk < K; kk += 64) {
#pragma unroll
        for (int it = 0; it < 4; ++it) {            // stage A: 128x64 bf16
            int q = it * 256 + t;
            int r = q >> 3, c8 = (q & 7) * 8;
            int gm = m0 + r;
            short8 v = {};
            if (gm < M) v = *reinterpret_cast<const short8*>(&A[(size_t)gm * K + kk + c8]);
            *reinterpret_cast<short8*>(&AsB[r * 128 + ((c8 * 2) ^ ((r & 7) << 4))]) = v;
        }
#pragma unroll
        for (int it = 0; it < 2; ++it) {            // stage B: 64x64 bf16
            int q = it * 256 + t;
            int r = q >> 3, c8 = (q & 7) * 8;
            short8 v = *reinterpret_cast<const short8*>(&BT[(size_t)(n0 + r) * K + kk + c8]);
            *reinterpret_cast<short8*>(&BsB[r * 128 + ((c8 * 2) ^ ((r & 7) << 4))]) = v;
        }
        __syncthreads();
#pragma unroll
        for (int kp = 0; kp < 2; ++kp) {
            const int koffb = kp * 64 + kgrp * 16;
            short8 b[2];
#pragma unroll
            for (int fn = 0; fn < 2; ++fn) {
                int col = wn * 32 + fn * 16 + frow;
                b[fn] = *reinterpret_cast<const short8*>(&BsB[col * 128 + (koffb ^ ((col & 7) << 4))]);
            }
#pragma unroll
            for (int fm = 0; fm < 4; ++fm) {
                int row = wm * 64 + fm * 16 + frow;
                short8 a = *reinterpret_cast<const short8*>(&AsB[row * 128 + (koffb ^ ((row & 7) << 4))]);
#pragma unroll
                for (int fn = 0; fn < 2; ++fn)
                    acc[fm][fn] = __builtin_amdgcn_mfma_f32_16x16x32_bf16(a, b[fn], acc[fm][fn], 0, 0, 0);
            }
        }
        __syncthreads();
    }

#pragma unroll
    for (int fm = 0; fm < 4; ++fm)
#pragma unroll
        for (int fn = 0; fn < 2; ++fn)
#pragma unroll
            for (int r = 0; r < 4; ++r) {
                int gm = m0 + wm * 64 + fm * 16 + kgrp * 4 + r;   // row = (lane>>4)*4+reg
                int gn = n0 + wn * 32 + fn * 16 + frow;           // col = lane&15
                if (gm >= M) continue;
                float v = acc[fm][fn][r];
                if (BIAS) v += bias[gn];
                if (RELU) v = fmaxf(v, 0.f);
                if (RES) v += res[(size_t)gm * NC + gn];
                stC(&C[(size_t)gm * NC + gn], v);
            }
}

// ---------------------------------------------------------------------------
// Edge pass 1: one wave per edge. u[e,h] = dot(G[dst,h,:], featbf[src,:]),
// clamp +-5, ex = exp(u); store ex, atomicAdd den.
// ---------------------------------------------------------------------------
__global__ __launch_bounds__(256) void edge_logits_kernel(
    const ushort* __restrict__ featbf, const ushort* __restrict__ GVO,
    const int* __restrict__ src, const int* __restrict__ dst,
    float* __restrict__ exb, float* __restrict__ den, int E)
{
    int wid = (int)((blockIdx.x * 256 + threadIdx.x) >> 6);
    int lane = threadIdx.x & 63;
    if (wid >= E) return;
    int s = src[wid], d = dst[wid];
    uint fv = reinterpret_cast<const uint*>(featbf)[(size_t)s * 64 + lane];
    float fx = bf_lo(fv), fy = bf_hi(fv);
    float myex = 0.f;
#pragma unroll
    for (int h = 0; h < 8; ++h) {
        uint gv = *reinterpret_cast<const uint*>(&GVO[(size_t)d * 2048 + h * 128 + 2 * lane]);
        float p = bf_lo(gv) * fx + bf_hi(gv) * fy;
#pragma unroll
        for (int off = 32; off; off >>= 1) p += __shfl_xor(p, off);
        float u = fminf(fmaxf(p, -5.f), 5.f);
        float ex = __expf(u);
        if (lane == h) myex = ex;
    }
    if (lane < 8) {
        exb[(size_t)wid * 8 + lane] = myex;
        atomicAdd(&den[(size_t)d * 8 + lane], myex);
    }
}

// ---------------------------------------------------------------------------
// Edge pass 2: one wave per edge. attn[dst,:] += sum_h a_eh * VO[src,h,:]
// ---------------------------------------------------------------------------
__global__ __launch_bounds__(256) void edge_agg_kernel(
    const ushort* __restrict__ GVO, const int* __restrict__ src,
    const int* __restrict__ dst, const float* __restrict__ exb,
    const float* __restrict__ den, float* __restrict__ attn, int E)
{
    int wid = (int)((blockIdx.x * 256 + threadIdx.x) >> 6);
    int lane = threadIdx.x & 63;
    if (wid >= E) return;
    int s = src[wid], d = dst[wid];
    float aval = 0.f;
    if (lane < 8) aval = exb[(size_t)wid * 8 + lane] / den[(size_t)d * 8 + lane];
    float acc0 = 0.f, acc1 = 0.f;
#pragma unroll
    for (int h = 0; h < 8; ++h) {
        float a = __shfl(aval, h);
        uint gv = *reinterpret_cast<const uint*>(&GVO[(size_t)s * 2048 + 1024 + h * 128 + 2 * lane]);
        acc0 += a * bf_lo(gv);
        acc1 += a * bf_hi(gv);
    }
    atomicAdd(&attn[(size_t)d * 128 + 2 * lane], acc0);
    atomicAdd(&attn[(size_t)d * 128 + 2 * lane + 1], acc1);
}

// ---------------------------------------------------------------------------
// LayerNorm over rows of 128. One wave per row. Optional 2nd addend,
// optional extra bf16 output.
// ---------------------------------------------------------------------------
template <bool TWO, bool BFOUT>
__global__ __launch_bounds__(256) void ln_kernel(
    const float* __restrict__ x, const float* __restrict__ y,
    const float* __restrict__ g, const float* __restrict__ b,
    float* __restrict__ out, ushort* __restrict__ outbf, int M)
{
    int row = (int)((blockIdx.x * 256 + threadIdx.x) >> 6);
    int lane = threadIdx.x & 63;
    if (row >= M) return;
    float2 v = reinterpret_cast<const float2*>(x)[(size_t)row * 64 + lane];
    if (TWO) {
        float2 w = reinterpret_cast<const float2*>(y)[(size_t)row * 64 + lane];
        v.x += w.x; v.y += w.y;
    }
    float sum = v.x + v.y;
#pragma unroll
    for (int off = 32; off; off >>= 1) sum += __shfl_xor(sum, off);
    float mean = sum * (1.f / 128.f);
    float cx = v.x - mean, cy = v.y - mean;
    float vs = cx * cx + cy * cy;
#pragma unroll
    for (int off = 32; off; off >>= 1) vs += __shfl_xor(vs, off);
    float r = rsqrtf(vs * (1.f / 128.f) + 1e-5f);
    float2 gg = reinterpret_cast<const float2*>(g)[lane];
    float2 bb = reinterpret_cast<const float2*>(b)[lane];
    float2 o;
    o.x = cx * r * gg.x + bb.x;
    o.y = cy * r * gg.y + bb.y;
    reinterpret_cast<float2*>(out)[(size_t)row * 64 + lane] = o;
    if (BFOUT) {
        ushort2 ob; ob.x = f2bf(o.x); ob.y = f2bf(o.y);
        reinterpret_cast<ushort2*>(outbf)[(size_t)row * 64 + lane] = ob;
    }
}

// ---------------------------------------------------------------------------
extern "C" void kernel_launch(void* const* d_in, const int* in_sizes, int n_in,
                              void* d_out, int out_size, void* d_ws, size_t ws_size,
                              hipStream_t stream)
{
    const float* feat = (const float*)d_in[0];
    const int*   src  = (const int*)d_in[1];
    const int*   dst  = (const int*)d_in[2];
    const float* Wq   = (const float*)d_in[3];
    const float* Wk   = (const float*)d_in[4];
    const float* Wv   = (const float*)d_in[5];
    const float* Wo   = (const float*)d_in[6];
    const float* g1   = (const float*)d_in[7];
    const float* b1   = (const float*)d_in[8];
    const float* W1   = (const float*)d_in[9];
    const float* bf1  = (const float*)d_in[10];
    const float* W2   = (const float*)d_in[11];
    const float* bf2  = (const float*)d_in[12];
    const float* g2   = (const float*)d_in[13];
    const float* b2   = (const float*)d_in[14];
    const int N = in_sizes[0] / 128;
    const int E = in_sizes[1];
    float* out = (float*)d_out;

    char* w = (char*)d_ws;
    auto alloc = [&](size_t bytes) {
        char* p = w;
        w += (bytes + 255) & ~(size_t)255;
        return p;
    };
    ushort* MPT   = (ushort*)alloc((size_t)2048 * 128 * 2);
    ushort* W1T   = (ushort*)alloc((size_t)512 * 128 * 2);
    ushort* W2T   = (ushort*)alloc((size_t)128 * 512 * 2);
    ushort* featbf= (ushort*)alloc((size_t)N * 128 * 2);
    ushort* GVO   = (ushort*)alloc((size_t)N * 2048 * 2);
    float*  exb   = (float*)alloc((size_t)E * 8 * 4);
    float*  den   = (float*)alloc((size_t)N * 8 * 4);
    float*  attn  = (float*)alloc((size_t)N * 128 * 4);
    float*  uh    = (float*)alloc((size_t)N * 128 * 4);
    ushort* uhbf  = (ushort*)alloc((size_t)N * 128 * 2);
    ushort* f1    = (ushort*)alloc((size_t)N * 512 * 2);
    float*  pre2  = (float*)alloc((size_t)N * 128 * 4);

    hipMemsetAsync(den, 0, (size_t)N * 8 * 4, stream);
    hipMemsetAsync(attn, 0, (size_t)N * 128 * 4, stream);

    // --- weight prep (tiny) ---
    f2bf_kernel<<<(N * 128 / 4 + 255) / 256, 256, 0, stream>>>(feat, featbf, N * 128 / 4);
    build_mpt_kernel<<<(128 * 2048 + 255) / 256, 256, 0, stream>>>(Wq, Wk, Wv, Wo, MPT);
    transp_bf_kernel<<<(128 * 512 + 255) / 256, 256, 0, stream>>>(W1, W1T, 128, 512);
    transp_bf_kernel<<<(512 * 128 + 255) / 256, 256, 0, stream>>>(W2, W2T, 512, 128);

    // --- GVO = feat @ [M | P]  (N x 2048, bf16 out) ---
    dim3 gv_grid(2048 / 64, (N + 127) / 128);
    gemm_mfma<ushort, false, false, false><<<gv_grid, 256, 0, stream>>>(
        featbf, MPT, nullptr, nullptr, GVO, N, 128, 2048);

    // --- edge passes ---
    int eblocks = (E + 3) / 4;
    edge_logits_kernel<<<eblocks, 256, 0, stream>>>(featbf, GVO, src, dst, exb, den, E);
    edge_agg_kernel<<<eblocks, 256, 0, stream>>>(GVO, src, dst, exb, den, attn, E);

    // --- LN1 (fp32 + bf16 out) ---
    int lblocks = (N + 3) / 4;
    ln_kernel<true, true><<<lblocks, 256, 0, stream>>>(feat, attn, g1, b1, uh, uhbf, N);

    // --- FFN ---
    dim3 f1_grid(512 / 64, (N + 127) / 128);
    gemm_mfma<ushort, true, true, false><<<f1_grid, 256, 0, stream>>>(
        uhbf, W1T, bf1, nullptr, f1, N, 128, 512);
    dim3 f2_grid(128 / 64, (N + 127) / 128);
    gemm_mfma<float, true, false, true><<<f2_grid, 256, 0, stream>>>(
        f1, W2T, bf2, uh, pre2, N, 512, 128);

    ln_kernel<false, false><<<lblocks, 256, 0, stream>>>(pre2, nullptr, g2, b2, out, nullptr, N);
}